// Round 22
// baseline (997.355 us; speedup 1.0000x reference)
//
#include <hip/hip_runtime.h>
#include <math.h>

#define BB 4
#define SS 4096
#define DD 128
#define KK 32
#define QB 32
#define CB 64
#define QPAD 132
#define FINF __builtin_inff()

// numpy transcription on zen4 pod CPU, bit-exact emulation:
//   gram = np.einsum('bid,bjd->bij', optimize=True) -> OpenBLAS sgemm:
//          per C element, single chained FMA over ascending k (K=128 < kc, no split-k)
//   sq   = np.sum(e*e, -1): AVX512-dispatched pairwise, n=128 one-shot:
//          8 accs x 16 lanes (acc m, lane l = p[16m+l]), per-lane tree
//          ((r0+r1)+(r2+r3))+((r4+r5)+(r6+r7)), then _mm512_reduce_add_ps halving:
//          stride 8, stride 4, (w0+w2)+(w1+w3)
//   d2   = (sq_i + sq_j) - 2.0f*gram : separate f32 roundings (numpy never contracts)
//   dist = np.sqrt(max(d2,0)) = correctly-rounded f32; diag = inf
//   top-32 ascending, stable (ties -> lowest index)

__global__ __launch_bounds__(256)
void knn_blas_avx512_kernel(const float* __restrict__ emb, float* __restrict__ out) {
    __shared__ float qs[QB][QPAD];
    __shared__ float cs[CB][QPAD];
    __shared__ float sqq[QB];
    __shared__ float sqs[CB];
    __shared__ float keybuf[QB][CB];
    __shared__ float ldist[QB][KK];
    __shared__ int   lidx[QB][KK];

    const int t    = threadIdx.x;
    const int lane = t & 63;
    const int wave = t >> 6;
    const int bx   = blockIdx.x;
    const int b    = bx >> 7;
    const int rb   = bx & 127;
    const int R0   = rb * QB;
    const float* embb = emb + (size_t)b * SS * DD;

    for (int i = t; i < QB * KK; i += 256) {
        ((float*)ldist)[i] = FINF;
        ((int*)lidx)[i]    = 0;
    }
    for (int i = t; i < QB * (DD / 4); i += 256) {
        int r = i >> 5, c4 = i & 31;
        *(float4*)&qs[r][c4 * 4] = *(const float4*)(embb + (size_t)(R0 + r) * DD + c4 * 4);
    }
    __syncthreads();

    // sq: AVX512 pairwise one-shot (8 accs x 16 lanes), halving reduce
#define NP_SQ16(row, dst)                                                         \
    {                                                                             \
        float s_[16];                                                             \
        _Pragma("unroll")                                                         \
        for (int l_ = 0; l_ < 16; ++l_) {                                         \
            const float t0_ = __fmul_rn((row)[  0 + l_], (row)[  0 + l_]);        \
            const float t1_ = __fmul_rn((row)[ 16 + l_], (row)[ 16 + l_]);        \
            const float t2_ = __fmul_rn((row)[ 32 + l_], (row)[ 32 + l_]);        \
            const float t3_ = __fmul_rn((row)[ 48 + l_], (row)[ 48 + l_]);        \
            const float t4_ = __fmul_rn((row)[ 64 + l_], (row)[ 64 + l_]);        \
            const float t5_ = __fmul_rn((row)[ 80 + l_], (row)[ 80 + l_]);        \
            const float t6_ = __fmul_rn((row)[ 96 + l_], (row)[ 96 + l_]);        \
            const float t7_ = __fmul_rn((row)[112 + l_], (row)[112 + l_]);        \
            s_[l_] = __fadd_rn(__fadd_rn(__fadd_rn(t0_, t1_), __fadd_rn(t2_, t3_)),\
                               __fadd_rn(__fadd_rn(t4_, t5_), __fadd_rn(t6_, t7_)));\
        }                                                                         \
        float u_[8];                                                              \
        _Pragma("unroll")                                                         \
        for (int l_ = 0; l_ < 8; ++l_) u_[l_] = __fadd_rn(s_[l_], s_[l_ + 8]);    \
        float w_[4];                                                              \
        _Pragma("unroll")                                                         \
        for (int l_ = 0; l_ < 4; ++l_) w_[l_] = __fadd_rn(u_[l_], u_[l_ + 4]);    \
        (dst) = __fadd_rn(__fadd_rn(w_[0], w_[2]), __fadd_rn(w_[1], w_[3]));      \
    }

    if (wave == 0 && lane < QB) {
        const float* row = qs[lane];
        NP_SQ16(row, sqq[lane])
    }

    const int rg = t >> 4, cg = t & 15;
    const int r0 = rg * 2, c0 = cg * 4;   // wave w owns rows 8w..8w+7

    for (int tile = 0; tile < SS / CB; ++tile) {
        const int j0 = tile * CB;
        __syncthreads();  // prev keys/select done; sqq ready (tile 0)

        for (int i = t; i < CB * (DD / 4); i += 256) {
            int r = i >> 5, c4 = i & 31;
            *(float4*)&cs[r][c4 * 4] = *(const float4*)(embb + (size_t)(j0 + r) * DD + c4 * 4);
        }
        __syncthreads();

        if (wave == 0) {
            const float* row = cs[lane];
            NP_SQ16(row, sqs[lane])
        }
        __syncthreads();

        // gram: OpenBLAS sgemm — single chained FMA per element, k ascending
        {
            const float* qrow0 = qs[r0];
            const float* qrow1 = qs[r0 + 1];
            const float* cr0 = cs[c0 + 0];
            const float* cr1 = cs[c0 + 1];
            const float* cr2 = cs[c0 + 2];
            const float* cr3 = cs[c0 + 3];
            float g00 = 0.f, g01 = 0.f, g02 = 0.f, g03 = 0.f;
            float g10 = 0.f, g11 = 0.f, g12 = 0.f, g13 = 0.f;
            #pragma unroll 8
            for (int k = 0; k < DD; ++k) {
                const float a0 = qrow0[k], a1 = qrow1[k];
                const float b0v = cr0[k], b1v = cr1[k], b2v = cr2[k], b3v = cr3[k];
                g00 = fmaf(a0, b0v, g00);
                g01 = fmaf(a0, b1v, g01);
                g02 = fmaf(a0, b2v, g02);
                g03 = fmaf(a0, b3v, g03);
                g10 = fmaf(a1, b0v, g10);
                g11 = fmaf(a1, b1v, g11);
                g12 = fmaf(a1, b2v, g12);
                g13 = fmaf(a1, b3v, g13);
            }
            const float gg[2][4] = {{g00, g01, g02, g03}, {g10, g11, g12, g13}};
            #pragma unroll
            for (int rr = 0; rr < 2; ++rr) {
                const int r  = r0 + rr;
                const int gi = R0 + r;
                #pragma unroll
                for (int cc = 0; cc < 4; ++cc) {
                    const int c = c0 + cc;
                    const int j = j0 + c;
                    float key;
                    if (j == gi) {
                        key = FINF;
                    } else {
                        const float tsum = __fadd_rn(sqq[r], sqs[c]);
                        float d2v = __fsub_rn(tsum, __fmul_rn(2.0f, gg[rr][cc]));
                        d2v = fmaxf(d2v, 0.0f);
                        key = (float)sqrt((double)d2v);  // correctly-rounded f32 sqrt
                    }
                    keybuf[r][c] = key;
                }
            }
        }
        // no barrier: wave w wrote rows 8w..8w+7 and selects the same rows

        // stable top-32 per row (ties -> lowest index)
        for (int rr = 0; rr < 8; ++rr) {
            const int r  = wave * 8 + rr;
            float tau = ldist[r][KK - 1];
            float v = keybuf[r][lane];
            const int j = j0 + lane;
            unsigned long long pend = __ballot(v < tau);
            while (pend) {
                const int s = __ffsll(pend) - 1;
                pend &= pend - 1;
                const float vs = __shfl(v, s);
                if (!(vs < tau)) continue;
                const int js = j0 + s;
                float myd = (lane < KK) ? ldist[r][lane] : FINF;
                int   myi = (lane < KK) ? lidx[r][lane] : 0;
                const float pd = __shfl_up(myd, 1);
                const int   pi = __shfl_up(myi, 1);
                const unsigned long long m = __ballot(myd <= vs);
                const int p = __popcll(m);
                float nd = myd; int ni = myi;
                if (lane < KK) {
                    if (lane == p)      { nd = vs; ni = js; }
                    else if (lane > p)  { nd = pd; ni = pi; }
                    ldist[r][lane] = nd;
                    lidx[r][lane]  = ni;
                }
                tau = __shfl(nd, KK - 1);
            }
        }
    }

    __syncthreads();
    for (int rr = 0; rr < 8; ++rr) {
        const int r = wave * 8 + rr;
        if (lane < KK) {
            const int gi = R0 + r;
            const size_t o = ((size_t)b * SS + gi) * KK + lane;
            out[o] = (float)lidx[r][lane];
            out[(size_t)BB * SS * KK + o] = ldist[r][lane];
        }
    }
}

extern "C" void kernel_launch(void* const* d_in, const int* in_sizes, int n_in,
                              void* d_out, int out_size, void* d_ws, size_t ws_size,
                              hipStream_t stream) {
    const float* emb = (const float*)d_in[0];
    float* out = (float*)d_out;
    (void)in_sizes; (void)n_in; (void)d_ws; (void)ws_size; (void)out_size;
    knn_blas_avx512_kernel<<<dim3(BB * (SS / QB)), dim3(256), 0, stream>>>(emb, out);
}

// Round 23
// 827.329 us; speedup vs baseline: 1.2055x; 1.2055x over previous
//
#include <hip/hip_runtime.h>
#include <math.h>

#define BB 4
#define SS 4096
#define DD 128
#define KK 32
#define QB 32
#define CB 64
#define FINF __builtin_inff()

// ---------- kernel 1: sq[b][j] = np.sum(e*e,-1), exact AVX512 pairwise one-shot ----------
// 16-lane group per row: lane gl holds s_[gl]; halving reduce in exact numpy order.
__global__ __launch_bounds__(256)
void sq_kernel(const float* __restrict__ emb, float* __restrict__ sqg) {
    const int t    = threadIdx.x;
    const int lane = t & 63;
    const int wid  = t >> 6;
    const int grp  = lane >> 4;
    const int gl   = lane & 15;
    const int row  = blockIdx.x * 16 + wid * 4 + grp;   // 0..16383
    const float* rp = emb + (size_t)row * DD;

    const float p0 = rp[  0 + gl], p1 = rp[ 16 + gl], p2 = rp[ 32 + gl], p3 = rp[ 48 + gl];
    const float p4 = rp[ 64 + gl], p5 = rp[ 80 + gl], p6 = rp[ 96 + gl], p7 = rp[112 + gl];
    const float t0 = __fmul_rn(p0, p0), t1 = __fmul_rn(p1, p1);
    const float t2 = __fmul_rn(p2, p2), t3 = __fmul_rn(p3, p3);
    const float t4 = __fmul_rn(p4, p4), t5 = __fmul_rn(p5, p5);
    const float t6 = __fmul_rn(p6, p6), t7 = __fmul_rn(p7, p7);
    const float s = __fadd_rn(__fadd_rn(__fadd_rn(t0, t1), __fadd_rn(t2, t3)),
                              __fadd_rn(__fadd_rn(t4, t5), __fadd_rn(t6, t7)));
    // _mm512_reduce_add_ps halving tree: stride 8, stride 4, (w0+w2)+(w1+w3)
    const int gbase = lane & 48;
    const float u = __fadd_rn(s, __shfl(s, gbase + ((lane & 15) + 8)));
    const float w = __fadd_rn(u, __shfl(u, gbase + ((lane & 15) + 4)));
    const float w0 = __shfl(w, gbase + 0), w1 = __shfl(w, gbase + 1);
    const float w2 = __shfl(w, gbase + 2), w3 = __shfl(w, gbase + 3);
    if (gl == 0) sqg[row] = __fadd_rn(__fadd_rn(w0, w2), __fadd_rn(w1, w3));
}

// ---------- kernel 2: gram (OpenBLAS chained FMA) + d2 + CR sqrt + stable top-32 ----------
// LDS: unpadded stride-128 rows, XOR granule swizzle for conflict-free b128 reads.
__device__ __forceinline__ float4 ldq(const float* buf, int r, int k4) {
    return *(const float4*)(buf + r * 128 + (((k4) ^ (r & 7)) << 2));
}
__device__ __forceinline__ float4 ldc(const float* buf, int c, int k4) {
    return *(const float4*)(buf + c * 128 + (((k4) ^ ((c >> 2) & 7)) << 2));
}

__global__ __launch_bounds__(256, 2)
void knn_main_kernel(const float* __restrict__ emb, const float* __restrict__ sqg,
                     float* __restrict__ out) {
    __shared__ float qs[QB * 128];
    __shared__ float cs[CB * 128];
    __shared__ float keybuf[QB][CB];
    __shared__ float ldist[QB][KK];
    __shared__ int   lidx[QB][KK];

    const int t    = threadIdx.x;
    const int lane = t & 63;
    const int wave = t >> 6;
    const int bx   = blockIdx.x;
    const int b    = bx >> 7;
    const int rb   = bx & 127;
    const int R0   = rb * QB;
    const float* embb = emb + (size_t)b * SS * DD;
    const float* sqb  = sqg + (size_t)b * SS;

    for (int i = t; i < QB * KK; i += 256) {
        ((float*)ldist)[i] = FINF;
        ((int*)lidx)[i]    = 0;
    }
    // stage qs with swizzle
    for (int i = t; i < QB * 32; i += 256) {
        const int r = i >> 5, c4 = i & 31;
        float4 v = *(const float4*)(embb + (size_t)(R0 + r) * DD + c4 * 4);
        *(float4*)&qs[r * 128 + ((c4 ^ (r & 7)) << 2)] = v;
    }

    const int rg = t >> 4, cg = t & 15;
    const int r0 = rg * 2, c0 = cg * 4;   // wave w computes AND selects rows 8w..8w+7
    const float sqr0 = sqb[R0 + r0];
    const float sqr1 = sqb[R0 + r0 + 1];

    for (int tile = 0; tile < SS / CB; ++tile) {
        const int j0 = tile * CB;
        __syncthreads();  // prev keys/select done before cs overwrite

        for (int i = t; i < CB * 32; i += 256) {
            const int r = i >> 5, c4 = i & 31;
            float4 v = *(const float4*)(embb + (size_t)(j0 + r) * DD + c4 * 4);
            *(float4*)&cs[r * 128 + ((c4 ^ ((r >> 2) & 7)) << 2)] = v;
        }
        __syncthreads();

        // gram: single chained FMA per element, k ascending (bit-exact OpenBLAS)
        float g00 = 0.f, g01 = 0.f, g02 = 0.f, g03 = 0.f;
        float g10 = 0.f, g11 = 0.f, g12 = 0.f, g13 = 0.f;
        #pragma unroll 4
        for (int k4 = 0; k4 < 32; ++k4) {
            const float4 q0 = ldq(qs, r0, k4);
            const float4 q1 = ldq(qs, r0 + 1, k4);
            const float4 b0 = ldc(cs, c0 + 0, k4);
            const float4 b1 = ldc(cs, c0 + 1, k4);
            const float4 b2 = ldc(cs, c0 + 2, k4);
            const float4 b3 = ldc(cs, c0 + 3, k4);
            g00 = fmaf(q0.x, b0.x, g00); g00 = fmaf(q0.y, b0.y, g00);
            g00 = fmaf(q0.z, b0.z, g00); g00 = fmaf(q0.w, b0.w, g00);
            g01 = fmaf(q0.x, b1.x, g01); g01 = fmaf(q0.y, b1.y, g01);
            g01 = fmaf(q0.z, b1.z, g01); g01 = fmaf(q0.w, b1.w, g01);
            g02 = fmaf(q0.x, b2.x, g02); g02 = fmaf(q0.y, b2.y, g02);
            g02 = fmaf(q0.z, b2.z, g02); g02 = fmaf(q0.w, b2.w, g02);
            g03 = fmaf(q0.x, b3.x, g03); g03 = fmaf(q0.y, b3.y, g03);
            g03 = fmaf(q0.z, b3.z, g03); g03 = fmaf(q0.w, b3.w, g03);
            g10 = fmaf(q1.x, b0.x, g10); g10 = fmaf(q1.y, b0.y, g10);
            g10 = fmaf(q1.z, b0.z, g10); g10 = fmaf(q1.w, b0.w, g10);
            g11 = fmaf(q1.x, b1.x, g11); g11 = fmaf(q1.y, b1.y, g11);
            g11 = fmaf(q1.z, b1.z, g11); g11 = fmaf(q1.w, b1.w, g11);
            g12 = fmaf(q1.x, b2.x, g12); g12 = fmaf(q1.y, b2.y, g12);
            g12 = fmaf(q1.z, b2.z, g12); g12 = fmaf(q1.w, b2.w, g12);
            g13 = fmaf(q1.x, b3.x, g13); g13 = fmaf(q1.y, b3.y, g13);
            g13 = fmaf(q1.z, b3.z, g13); g13 = fmaf(q1.w, b3.w, g13);
        }

        // d2 + CR f32 sqrt keys (bit-exact numpy assembly)
        {
            const float sq_c0 = sqb[j0 + c0 + 0];
            const float sq_c1 = sqb[j0 + c0 + 1];
            const float sq_c2 = sqb[j0 + c0 + 2];
            const float sq_c3 = sqb[j0 + c0 + 3];
            const float gg[2][4] = {{g00, g01, g02, g03}, {g10, g11, g12, g13}};
            const float sqr[2] = {sqr0, sqr1};
            const float sqc[4] = {sq_c0, sq_c1, sq_c2, sq_c3};
            #pragma unroll
            for (int rr = 0; rr < 2; ++rr) {
                const int r  = r0 + rr;
                const int gi = R0 + r;
                float keys[4];
                #pragma unroll
                for (int cc = 0; cc < 4; ++cc) {
                    const int j = j0 + c0 + cc;
                    if (j == gi) {
                        keys[cc] = FINF;
                    } else {
                        const float tsum = __fadd_rn(sqr[rr], sqc[cc]);
                        float d2v = __fsub_rn(tsum, __fmul_rn(2.0f, gg[rr][cc]));
                        d2v = fmaxf(d2v, 0.0f);
                        keys[cc] = (float)sqrt((double)d2v);
                    }
                }
                *(float4*)&keybuf[r][c0] = make_float4(keys[0], keys[1], keys[2], keys[3]);
            }
        }
        // no barrier: wave w wrote rows 8w..8w+7 and selects the same rows

        // stable top-32 per row (ties -> lowest index)
        for (int rr = 0; rr < 8; ++rr) {
            const int r  = wave * 8 + rr;
            float tau = ldist[r][KK - 1];
            float v = keybuf[r][lane];
            const int j = j0 + lane;
            unsigned long long pend = __ballot(v < tau);
            while (pend) {
                const int s = __ffsll(pend) - 1;
                pend &= pend - 1;
                const float vs = __shfl(v, s);
                if (!(vs < tau)) continue;
                const int js = j0 + s;
                float myd = (lane < KK) ? ldist[r][lane] : FINF;
                int   myi = (lane < KK) ? lidx[r][lane] : 0;
                const float pd = __shfl_up(myd, 1);
                const int   pi = __shfl_up(myi, 1);
                const unsigned long long m = __ballot(myd <= vs);
                const int p = __popcll(m);
                float nd = myd; int ni = myi;
                if (lane < KK) {
                    if (lane == p)      { nd = vs; ni = js; }
                    else if (lane > p)  { nd = pd; ni = pi; }
                    ldist[r][lane] = nd;
                    lidx[r][lane]  = ni;
                }
                tau = __shfl(nd, KK - 1);
            }
        }
    }

    __syncthreads();
    for (int rr = 0; rr < 8; ++rr) {
        const int r = wave * 8 + rr;
        if (lane < KK) {
            const int gi = R0 + r;
            const size_t o = ((size_t)b * SS + gi) * KK + lane;
            out[o] = (float)lidx[r][lane];
            out[(size_t)BB * SS * KK + o] = ldist[r][lane];
        }
    }
}

extern "C" void kernel_launch(void* const* d_in, const int* in_sizes, int n_in,
                              void* d_out, int out_size, void* d_ws, size_t ws_size,
                              hipStream_t stream) {
    const float* emb = (const float*)d_in[0];
    float* out = (float*)d_out;
    float* sqg = (float*)d_ws;   // 4*4096 floats = 64 KB scratch
    (void)in_sizes; (void)n_in; (void)ws_size; (void)out_size;
    sq_kernel<<<dim3(BB * SS / 16), dim3(256), 0, stream>>>(emb, sqg);
    knn_main_kernel<<<dim3(BB * (SS / QB)), dim3(256), 0, stream>>>(emb, sqg, out);
}

// Round 24
// 732.727 us; speedup vs baseline: 1.3612x; 1.1291x over previous
//
#include <hip/hip_runtime.h>
#include <hip/hip_bf16.h>
#include <math.h>

#define BB 4
#define SS 4096
#define DD 128
#define KK 32
#define QB 32
#define CB 64
#define NC 64
#define FINF __builtin_inff()

typedef __attribute__((ext_vector_type(8))) short short8v;
typedef __attribute__((ext_vector_type(4))) float f32x4;

__device__ __forceinline__ unsigned short f2bf(float x) {
    __hip_bfloat16 h = __float2bfloat16(x);
    return *reinterpret_cast<unsigned short*>(&h);
}

// ---------- kernel 1: exact sq (AVX512 one-shot pairwise), proven ----------
__global__ __launch_bounds__(256)
void sq_kernel(const float* __restrict__ emb, float* __restrict__ sqg) {
    const int t    = threadIdx.x;
    const int lane = t & 63;
    const int wid  = t >> 6;
    const int grp  = lane >> 4;
    const int gl   = lane & 15;
    const int row  = blockIdx.x * 16 + wid * 4 + grp;
    const float* rp = emb + (size_t)row * DD;

    const float p0 = rp[  0 + gl], p1 = rp[ 16 + gl], p2 = rp[ 32 + gl], p3 = rp[ 48 + gl];
    const float p4 = rp[ 64 + gl], p5 = rp[ 80 + gl], p6 = rp[ 96 + gl], p7 = rp[112 + gl];
    const float t0 = __fmul_rn(p0, p0), t1 = __fmul_rn(p1, p1);
    const float t2 = __fmul_rn(p2, p2), t3 = __fmul_rn(p3, p3);
    const float t4 = __fmul_rn(p4, p4), t5 = __fmul_rn(p5, p5);
    const float t6 = __fmul_rn(p6, p6), t7 = __fmul_rn(p7, p7);
    const float s = __fadd_rn(__fadd_rn(__fadd_rn(t0, t1), __fadd_rn(t2, t3)),
                              __fadd_rn(__fadd_rn(t4, t5), __fadd_rn(t6, t7)));
    const int gbase = lane & 48;
    const float u = __fadd_rn(s, __shfl(s, gbase + ((lane & 15) + 8)));
    const float w = __fadd_rn(u, __shfl(u, gbase + ((lane & 15) + 4)));
    const float w0 = __shfl(w, gbase + 0), w1 = __shfl(w, gbase + 1);
    const float w2 = __shfl(w, gbase + 2), w3 = __shfl(w, gbase + 3);
    if (gl == 0) sqg[row] = __fadd_rn(__fadd_rn(w0, w2), __fadd_rn(w1, w3));
}

// ---------- kernel 2: MFMA bf16 screen (top-64 approx) + exact re-verify ----------
__global__ __launch_bounds__(256, 2)
void knn_screen_kernel(const float* __restrict__ emb, const float* __restrict__ sqg,
                       float* __restrict__ out) {
    __shared__ unsigned short qsb[QB][128];   // bf16 q, XOR-swizzled 16B granules
    __shared__ unsigned short csb[CB][128];   // bf16 c tile, swizzled
    __shared__ float qsf[QB][128];            // f32 q (linear) for exact phase
    __shared__ float keybuf[QB][CB];
    __shared__ float ldist[QB][NC];
    __shared__ int   lidx[QB][NC];
    __shared__ float sqq_s[QB];
    __shared__ float sqc_s[CB];

    const int t    = threadIdx.x;
    const int lane = t & 63;
    const int wave = t >> 6;
    const int bx   = blockIdx.x;
    const int b    = bx >> 7;
    const int rb   = bx & 127;
    const int R0   = rb * QB;
    const float* embb = emb + (size_t)b * SS * DD;
    const float* sqb  = sqg + (size_t)b * SS;

    for (int i = t; i < QB * NC; i += 256) {
        ((float*)ldist)[i] = FINF;
        ((int*)lidx)[i]    = 0;
    }
    // stage q: f32 linear + bf16 swizzled
    for (int i = t; i < QB * 32; i += 256) {
        const int r = i >> 5, c4 = i & 31;
        float4 v = *(const float4*)(embb + (size_t)(R0 + r) * DD + c4 * 4);
        *(float4*)&qsf[r][c4 * 4] = v;
        const int G = c4 >> 1;
        unsigned short* dst = &qsb[r][((G ^ (r & 7)) << 3) + (c4 & 1) * 4];
        dst[0] = f2bf(v.x); dst[1] = f2bf(v.y); dst[2] = f2bf(v.z); dst[3] = f2bf(v.w);
    }
    if (t < QB) sqq_s[t] = sqb[R0 + t];

    const int rowblk  = (wave >> 1) * 16;
    const int colhalf = (wave & 1) * 32;

    for (int tile = 0; tile < SS / CB; ++tile) {
        const int j0 = tile * CB;

        // phase A: stage c tile (bf16 swizzled) + sqc
        for (int i = t; i < CB * 32; i += 256) {
            const int r = i >> 5, c4 = i & 31;
            float4 v = *(const float4*)(embb + (size_t)(j0 + r) * DD + c4 * 4);
            const int G = c4 >> 1;
            unsigned short* dst = &csb[r][((G ^ (r & 7)) << 3) + (c4 & 1) * 4];
            dst[0] = f2bf(v.x); dst[1] = f2bf(v.y); dst[2] = f2bf(v.z); dst[3] = f2bf(v.w);
        }
        if (t < CB) sqc_s[t] = sqb[j0 + t];
        __syncthreads();

        // phase B: MFMA gram + assemble approx d2 keys
        f32x4 acc0 = {0.f, 0.f, 0.f, 0.f};
        f32x4 acc1 = {0.f, 0.f, 0.f, 0.f};
        const int arow = rowblk + (lane & 15);
        const int bcol0 = colhalf + (lane & 15);
        const int bcol1 = colhalf + 16 + (lane & 15);
        #pragma unroll
        for (int ks = 0; ks < 4; ++ks) {
            const int kg = ks * 4 + (lane >> 4);
            short8v a  = *(const short8v*)&qsb[arow][(kg ^ (arow & 7)) << 3];
            short8v b0 = *(const short8v*)&csb[bcol0][(kg ^ (bcol0 & 7)) << 3];
            short8v b1 = *(const short8v*)&csb[bcol1][(kg ^ (bcol1 & 7)) << 3];
            acc0 = __builtin_amdgcn_mfma_f32_16x16x32_bf16(a, b0, acc0, 0, 0, 0);
            acc1 = __builtin_amdgcn_mfma_f32_16x16x32_bf16(a, b1, acc1, 0, 0, 0);
        }
        {
            const int grow_base = rowblk + (lane >> 4) * 4;
            const int gcol0 = colhalf + (lane & 15);
            const int gcol1 = colhalf + 16 + (lane & 15);
            #pragma unroll
            for (int q = 0; q < 4; ++q) {
                const int grow = grow_base + q;
                float d2a = sqq_s[grow] + sqc_s[gcol0] - 2.0f * acc0[q];
                float d2b = sqq_s[grow] + sqc_s[gcol1] - 2.0f * acc1[q];
                if (R0 + grow == j0 + gcol0) d2a = FINF;
                if (R0 + grow == j0 + gcol1) d2b = FINF;
                keybuf[grow][gcol0] = d2a;
                keybuf[grow][gcol1] = d2b;
            }
        }
        __syncthreads();

        // phase C: approx top-64 insertion (proven machinery; all 64 lanes are list)
        for (int rr = 0; rr < 8; ++rr) {
            const int r = wave * 8 + rr;
            float tau = ldist[r][NC - 1];
            float v = keybuf[r][lane];
            unsigned long long pend = __ballot(v < tau);
            while (pend) {
                const int s = __ffsll(pend) - 1;
                pend &= pend - 1;
                const float vs = __shfl(v, s);
                if (!(vs < tau)) continue;
                const int js = j0 + s;
                float myd = ldist[r][lane];
                int   myi = lidx[r][lane];
                const float pd = __shfl_up(myd, 1);
                const int   pi = __shfl_up(myi, 1);
                const unsigned long long m = __ballot(myd <= vs);
                const int p = __popcll(m);
                float nd = myd; int ni = myi;
                if (lane == p)      { nd = vs; ni = js; }
                else if (lane > p)  { nd = pd; ni = pi; }
                ldist[r][lane] = nd;
                lidx[r][lane]  = ni;
                tau = __shfl(nd, NC - 1);
            }
        }
        // next tile's phase A follows; barrier before B protects csb/keybuf
    }

    __syncthreads();

    // ---------- exact phase: golden-exact keys for the 64 candidates ----------
    for (int rr = 0; rr < 8; ++rr) {
        const int r  = wave * 8 + rr;
        const int gi = R0 + r;
        const int ce = lidx[r][lane];          // this lane's candidate
        const float* cp = embb + (size_t)ce * DD;
        // gram: single chained FMA, k ascending (bit-exact OpenBLAS order)
        float g = 0.f;
        #pragma unroll 8
        for (int k4 = 0; k4 < 32; ++k4) {
            const float4 qv = *(const float4*)&qsf[r][k4 * 4];   // broadcast
            const float4 cv = *(const float4*)(cp + k4 * 4);
            g = fmaf(qv.x, cv.x, g);
            g = fmaf(qv.y, cv.y, g);
            g = fmaf(qv.z, cv.z, g);
            g = fmaf(qv.w, cv.w, g);
        }
        const float tsum = __fadd_rn(sqq_s[r], sqb[ce]);
        float d2v = __fsub_rn(tsum, __fmul_rn(2.0f, g));
        d2v = fmaxf(d2v, 0.0f);
        const float ke = (float)sqrt((double)d2v);   // CR f32 sqrt
        // stable rank among 64 by (key, idx) — ties lowest index (golden semantics)
        int rank = 0;
        for (int c = 0; c < NC; ++c) {
            const float kc = __shfl(ke, c);
            const int   jc = __shfl(ce, c);
            rank += (kc < ke) || (kc == ke && jc < ce);
        }
        if (rank < KK) {
            const size_t o = ((size_t)b * SS + gi) * KK + rank;
            out[o] = (float)ce;
            out[(size_t)BB * SS * KK + o] = ke;
        }
    }
}

extern "C" void kernel_launch(void* const* d_in, const int* in_sizes, int n_in,
                              void* d_out, int out_size, void* d_ws, size_t ws_size,
                              hipStream_t stream) {
    const float* emb = (const float*)d_in[0];
    float* out = (float*)d_out;
    float* sqg = (float*)d_ws;   // 64 KB scratch
    (void)in_sizes; (void)n_in; (void)ws_size; (void)out_size;
    sq_kernel<<<dim3(BB * SS / 16), dim3(256), 0, stream>>>(emb, sqg);
    knn_screen_kernel<<<dim3(BB * (SS / QB)), dim3(256), 0, stream>>>(emb, sqg, out);
}

// Round 25
// 500.122 us; speedup vs baseline: 1.9942x; 1.4651x over previous
//
#include <hip/hip_runtime.h>
#include <hip/hip_bf16.h>
#include <math.h>

#define BB 4
#define SS 4096
#define DD 128
#define KK 32
#define QB 16
#define CB 64
#define NC 64
#define FINF __builtin_inff()

typedef __attribute__((ext_vector_type(8))) short short8v;
typedef __attribute__((ext_vector_type(4))) float f32x4;

__device__ __forceinline__ unsigned short f2bf(float x) {
    __hip_bfloat16 h = __float2bfloat16(x);
    return *reinterpret_cast<unsigned short*>(&h);
}

// ---------- kernel 1: exact sq (AVX512 one-shot pairwise), proven ----------
__global__ __launch_bounds__(256)
void sq_kernel(const float* __restrict__ emb, float* __restrict__ sqg) {
    const int t    = threadIdx.x;
    const int lane = t & 63;
    const int wid  = t >> 6;
    const int grp  = lane >> 4;
    const int gl   = lane & 15;
    const int row  = blockIdx.x * 16 + wid * 4 + grp;
    const float* rp = emb + (size_t)row * DD;

    const float p0 = rp[  0 + gl], p1 = rp[ 16 + gl], p2 = rp[ 32 + gl], p3 = rp[ 48 + gl];
    const float p4 = rp[ 64 + gl], p5 = rp[ 80 + gl], p6 = rp[ 96 + gl], p7 = rp[112 + gl];
    const float t0 = __fmul_rn(p0, p0), t1 = __fmul_rn(p1, p1);
    const float t2 = __fmul_rn(p2, p2), t3 = __fmul_rn(p3, p3);
    const float t4 = __fmul_rn(p4, p4), t5 = __fmul_rn(p5, p5);
    const float t6 = __fmul_rn(p6, p6), t7 = __fmul_rn(p7, p7);
    const float s = __fadd_rn(__fadd_rn(__fadd_rn(t0, t1), __fadd_rn(t2, t3)),
                              __fadd_rn(__fadd_rn(t4, t5), __fadd_rn(t6, t7)));
    const int gbase = lane & 48;
    const float u = __fadd_rn(s, __shfl(s, gbase + ((lane & 15) + 8)));
    const float w = __fadd_rn(u, __shfl(u, gbase + ((lane & 15) + 4)));
    const float w0 = __shfl(w, gbase + 0), w1 = __shfl(w, gbase + 1);
    const float w2 = __shfl(w, gbase + 2), w3 = __shfl(w, gbase + 3);
    if (gl == 0) sqg[row] = __fadd_rn(__fadd_rn(w0, w2), __fadd_rn(w1, w3));
}

// ---------- kernel 2: MFMA bf16 screen (reg-resident top-64) + exact re-verify ----------
__global__ __launch_bounds__(256, 4)
void knn_screen2_kernel(const float* __restrict__ emb, const float* __restrict__ sqg,
                        float* __restrict__ out) {
    __shared__ unsigned short qsb[QB][128];   // bf16 q, XOR-swizzled 16B granules (4 KB)
    __shared__ unsigned short csb[CB][128];   // bf16 c tile, swizzled (16 KB)
    __shared__ float qsf[QB][128];            // f32 q (linear) for exact phase (8 KB)
    __shared__ float keybuf[QB][CB];          // (4 KB)
    __shared__ float sqq_s[QB];
    __shared__ float sqc_s[CB];

    const int t    = threadIdx.x;
    const int lane = t & 63;
    const int wave = t >> 6;
    const int bx   = blockIdx.x;
    const int b    = bx >> 8;                  // 256 row-blocks per batch
    const int rb   = bx & 255;
    const int R0   = rb * QB;
    const float* embb = emb + (size_t)b * SS * DD;
    const float* sqb  = sqg + (size_t)b * SS;

    // stage q: f32 linear + bf16 swizzled
    for (int i = t; i < QB * 32; i += 256) {
        const int r = i >> 5, c4 = i & 31;
        float4 v = *(const float4*)(embb + (size_t)(R0 + r) * DD + c4 * 4);
        *(float4*)&qsf[r][c4 * 4] = v;
        const int G = c4 >> 1;
        unsigned short* dst = &qsb[r][((G ^ (r & 7)) << 3) + (c4 & 1) * 4];
        dst[0] = f2bf(v.x); dst[1] = f2bf(v.y); dst[2] = f2bf(v.z); dst[3] = f2bf(v.w);
    }
    if (t < QB) sqq_s[t] = sqb[R0 + t];

    // register-resident top-64 list: one entry per lane, per owned row
    float dl[4] = {FINF, FINF, FINF, FINF};
    int   il[4] = {0, 0, 0, 0};
    float tau[4] = {FINF, FINF, FINF, FINF};

    const int arow = lane & 15;               // A-fragment row (proven R24 mapping)
    const int bcol = wave * 16 + (lane & 15); // B-fragment col for this wave's chunk

    for (int tile = 0; tile < SS / CB; ++tile) {
        const int j0 = tile * CB;

        // phase A: stage c tile (bf16 swizzled) + sqc
        for (int i = t; i < CB * 32; i += 256) {
            const int r = i >> 5, c4 = i & 31;
            float4 v = *(const float4*)(embb + (size_t)(j0 + r) * DD + c4 * 4);
            const int G = c4 >> 1;
            unsigned short* dst = &csb[r][((G ^ (r & 7)) << 3) + (c4 & 1) * 4];
            dst[0] = f2bf(v.x); dst[1] = f2bf(v.y); dst[2] = f2bf(v.z); dst[3] = f2bf(v.w);
        }
        if (t < CB) sqc_s[t] = sqb[j0 + t];
        __syncthreads();

        // phase B: MFMA gram (16 rows x 16 cols per wave) + assemble approx d2 keys
        f32x4 acc = {0.f, 0.f, 0.f, 0.f};
        #pragma unroll
        for (int ks = 0; ks < 4; ++ks) {
            const int kg = ks * 4 + (lane >> 4);
            short8v a  = *(const short8v*)&qsb[arow][(kg ^ (arow & 7)) << 3];
            short8v bf = *(const short8v*)&csb[bcol][(kg ^ (bcol & 7)) << 3];
            acc = __builtin_amdgcn_mfma_f32_16x16x32_bf16(a, bf, acc, 0, 0, 0);
        }
        {
            const int grow_base = (lane >> 4) * 4;
            const int gcol = wave * 16 + (lane & 15);
            #pragma unroll
            for (int q = 0; q < 4; ++q) {
                const int grow = grow_base + q;
                float d2v = sqq_s[grow] + sqc_s[gcol] - 2.0f * acc[q];
                if (R0 + grow == j0 + gcol) d2v = FINF;
                keybuf[grow][gcol] = d2v;
            }
        }
        __syncthreads();

        // phase C: reg-list insertion; wave w owns rows w*4 .. w*4+3
        #pragma unroll
        for (int rr = 0; rr < 4; ++rr) {
            const int r = wave * 4 + rr;
            const float v = keybuf[r][lane];
            unsigned long long pend = __ballot(v < tau[rr]);
            while (pend) {
                const int s = __ffsll(pend) - 1;
                pend &= pend - 1;
                const float vs = __shfl(v, s);
                if (!(vs < tau[rr])) continue;
                const int js = j0 + s;
                const float pd = __shfl_up(dl[rr], 1);
                const int   pi = __shfl_up(il[rr], 1);
                const unsigned long long m = __ballot(dl[rr] <= vs);
                const int p = __popcll(m);
                if (lane == p)      { dl[rr] = vs; il[rr] = js; }
                else if (lane > p)  { dl[rr] = pd; il[rr] = pi; }
                tau[rr] = __shfl(dl[rr], NC - 1);
            }
        }
        // next A overwrites csb/keybuf only after the A->B barrier; safe.
    }

    __syncthreads();

    // ---------- exact phase: golden-exact keys for the 64 candidates ----------
    #pragma unroll
    for (int rr = 0; rr < 4; ++rr) {
        const int r  = wave * 4 + rr;
        const int gi = R0 + r;
        const int ce = il[rr];
        const float* cp = embb + (size_t)ce * DD;
        // gram: single chained FMA, k ascending (bit-exact OpenBLAS order)
        float g = 0.f;
        #pragma unroll 8
        for (int k4 = 0; k4 < 32; ++k4) {
            const float4 qv = *(const float4*)&qsf[r][k4 * 4];   // LDS broadcast
            const float4 cv = *(const float4*)(cp + k4 * 4);
            g = fmaf(qv.x, cv.x, g);
            g = fmaf(qv.y, cv.y, g);
            g = fmaf(qv.z, cv.z, g);
            g = fmaf(qv.w, cv.w, g);
        }
        const float tsum = __fadd_rn(sqq_s[r], sqb[ce]);
        float d2v = __fsub_rn(tsum, __fmul_rn(2.0f, g));
        d2v = fmaxf(d2v, 0.0f);
        const float ke = (float)sqrt((double)d2v);   // CR f32 sqrt
        // stable rank among 64 by (key, idx) — ties lowest index (golden semantics)
        int rank = 0;
        for (int c = 0; c < NC; ++c) {
            const float kc = __shfl(ke, c);
            const int   jc = __shfl(ce, c);
            rank += (kc < ke) || (kc == ke && jc < ce);
        }
        if (rank < KK) {
            const size_t o = ((size_t)b * SS + gi) * KK + rank;
            out[o] = (float)ce;
            out[(size_t)BB * SS * KK + o] = ke;
        }
    }
}

extern "C" void kernel_launch(void* const* d_in, const int* in_sizes, int n_in,
                              void* d_out, int out_size, void* d_ws, size_t ws_size,
                              hipStream_t stream) {
    const float* emb = (const float*)d_in[0];
    float* out = (float*)d_out;
    float* sqg = (float*)d_ws;   // 64 KB scratch
    (void)in_sizes; (void)n_in; (void)ws_size; (void)out_size;
    sq_kernel<<<dim3(BB * SS / 16), dim3(256), 0, stream>>>(emb, sqg);
    knn_screen2_kernel<<<dim3(BB * (SS / QB)), dim3(256), 0, stream>>>(emb, sqg, out);
}

// Round 26
// 440.648 us; speedup vs baseline: 2.2634x; 1.1350x over previous
//
#include <hip/hip_runtime.h>
#include <hip/hip_bf16.h>
#include <math.h>
#include <stdint.h>

#define BB 4
#define SS 4096
#define DD 128
#define KK 32
#define QB 16
#define CB 64
#define NC 64
#define FINF __builtin_inff()

typedef __attribute__((ext_vector_type(8))) short short8v;
typedef __attribute__((ext_vector_type(4))) float f32x4;

__device__ __forceinline__ unsigned short f2bf(float x) {
    __hip_bfloat16 h = __float2bfloat16(x);
    return *reinterpret_cast<unsigned short*>(&h);
}

__device__ __forceinline__ void gload16(const void* gsrc, void* ldsdst) {
    __builtin_amdgcn_global_load_lds(
        (const __attribute__((address_space(1))) unsigned int*)gsrc,
        (__attribute__((address_space(3))) unsigned int*)ldsdst, 16, 0, 0);
}

// ---------- prep: exact sq (proven) + bf16 pre-swizzled copy of emb ----------
__global__ __launch_bounds__(256)
void prep_kernel(const float* __restrict__ emb, float* __restrict__ sqg,
                 unsigned short* __restrict__ ebf) {
    const int t    = threadIdx.x;
    const int lane = t & 63;
    const int wid  = t >> 6;
    const int grp  = lane >> 4;
    const int gl   = lane & 15;
    const int row  = blockIdx.x * 16 + wid * 4 + grp;
    const float* rp = emb + (size_t)row * DD;

    // exact AVX512 one-shot pairwise sq
    const float p0 = rp[  0 + gl], p1 = rp[ 16 + gl], p2 = rp[ 32 + gl], p3 = rp[ 48 + gl];
    const float p4 = rp[ 64 + gl], p5 = rp[ 80 + gl], p6 = rp[ 96 + gl], p7 = rp[112 + gl];
    const float t0 = __fmul_rn(p0, p0), t1 = __fmul_rn(p1, p1);
    const float t2 = __fmul_rn(p2, p2), t3 = __fmul_rn(p3, p3);
    const float t4 = __fmul_rn(p4, p4), t5 = __fmul_rn(p5, p5);
    const float t6 = __fmul_rn(p6, p6), t7 = __fmul_rn(p7, p7);
    const float s = __fadd_rn(__fadd_rn(__fadd_rn(t0, t1), __fadd_rn(t2, t3)),
                              __fadd_rn(__fadd_rn(t4, t5), __fadd_rn(t6, t7)));
    const int gbase = lane & 48;
    const float u = __fadd_rn(s, __shfl(s, gbase + ((lane & 15) + 8)));
    const float w = __fadd_rn(u, __shfl(u, gbase + ((lane & 15) + 4)));
    const float w0 = __shfl(w, gbase + 0), w1 = __shfl(w, gbase + 1);
    const float w2 = __shfl(w, gbase + 2), w3 = __shfl(w, gbase + 3);
    if (gl == 0) sqg[row] = __fadd_rn(__fadd_rn(w0, w2), __fadd_rn(w1, w3));

    // bf16 conversion, granule-swizzled: granule g lands at (g ^ (row&7))
    const float4 va = *(const float4*)(rp + gl * 8);
    const float4 vb = *(const float4*)(rp + gl * 8 + 4);
    short8v pk;
    pk[0] = (short)f2bf(va.x); pk[1] = (short)f2bf(va.y);
    pk[2] = (short)f2bf(va.z); pk[3] = (short)f2bf(va.w);
    pk[4] = (short)f2bf(vb.x); pk[5] = (short)f2bf(vb.y);
    pk[6] = (short)f2bf(vb.z); pk[7] = (short)f2bf(vb.w);
    const int gsw = gl ^ (row & 7);
    *(short8v*)&ebf[(size_t)row * 128 + gsw * 8] = pk;
}

// ---------- fast main: gload_lds staging + MFMA screen + exact re-verify ----------
__global__ __launch_bounds__(256, 4)
void knn_fast_kernel(const float* __restrict__ emb, const float* __restrict__ sqg,
                     const unsigned short* __restrict__ ebf, float* __restrict__ out) {
    __shared__ unsigned short qsb[QB][128];   // 4 KB  (swizzled bf16 q)
    __shared__ unsigned short csb[CB][128];   // 16 KB (swizzled bf16 c tile)
    __shared__ float qsf[QB][128];            // 8 KB  (f32 q for exact phase)
    __shared__ float keybuf[QB][CB];          // 4 KB
    __shared__ float sqq_s[QB];

    const int t    = threadIdx.x;
    const int lane = t & 63;
    const int wave = t >> 6;
    const int bx   = blockIdx.x;
    const int b    = bx >> 8;
    const int rb   = bx & 255;
    const int R0   = rb * QB;
    const float* embb = emb + (size_t)b * SS * DD;
    const float* sqb  = sqg + (size_t)b * SS;
    const unsigned short* ebfb = ebf + (size_t)b * SS * 128;

    // stage q: bf16 via gload_lds (1 KB/wave), f32 via normal loads
    gload16((const char*)ebfb + (size_t)R0 * 256 + wave * 1024 + lane * 16,
            (char*)&qsb[0][0] + wave * 1024);
    for (int i = t; i < QB * 32; i += 256) {
        const int r = i >> 5, c4 = i & 31;
        *(float4*)&qsf[r][c4 * 4] = *(const float4*)(embb + (size_t)(R0 + r) * DD + c4 * 4);
    }
    if (t < QB) sqq_s[t] = sqb[R0 + t];

    float dl[4]  = {FINF, FINF, FINF, FINF};
    int   il[4]  = {0, 0, 0, 0};
    float tau[4] = {FINF, FINF, FINF, FINF};

    const int arow = lane & 15;
    const int bcol = wave * 16 + (lane & 15);

    // preload tile 0
    #pragma unroll
    for (int c2 = 0; c2 < 4; ++c2)
        gload16((const char*)ebfb + (wave * 4 + c2) * 1024 + lane * 16,
                (char*)&csb[0][0] + (wave * 4 + c2) * 1024);
    __syncthreads();   // implicit vmcnt(0): qsb+csb ready

    for (int tile = 0; tile < SS / CB; ++tile) {
        const int j0 = tile * CB;

        // phase B: MFMA gram + approx d2 keys
        f32x4 acc = {0.f, 0.f, 0.f, 0.f};
        #pragma unroll
        for (int ks = 0; ks < 4; ++ks) {
            const int kg = ks * 4 + (lane >> 4);
            short8v a  = *(const short8v*)&qsb[arow][(kg ^ (arow & 7)) << 3];
            short8v bf = *(const short8v*)&csb[bcol][(kg ^ (bcol & 7)) << 3];
            acc = __builtin_amdgcn_mfma_f32_16x16x32_bf16(a, bf, acc, 0, 0, 0);
        }
        {
            const float sqcv = sqb[j0 + bcol];     // L2 read, 16 distinct/wave
            const int grow_base = (lane >> 4) * 4;
            #pragma unroll
            for (int q = 0; q < 4; ++q) {
                const int grow = grow_base + q;
                float d2v = sqq_s[grow] + sqcv - 2.0f * acc[q];
                if (R0 + grow == j0 + bcol) d2v = FINF;
                keybuf[grow][bcol] = d2v;
            }
        }
        __syncthreads();   // (1) csb consumed, keybuf ready

        // prefetch next tile into csb (overlaps with phase C)
        if (tile + 1 < SS / CB) {
            const size_t base = (size_t)(j0 + CB) * 256;
            #pragma unroll
            for (int c2 = 0; c2 < 4; ++c2)
                gload16((const char*)ebfb + base + (wave * 4 + c2) * 1024 + lane * 16,
                        (char*)&csb[0][0] + (wave * 4 + c2) * 1024);
        }

        // phase C: reg-list top-64 insertion; wave owns rows wave*4..wave*4+3
        #pragma unroll
        for (int rr = 0; rr < 4; ++rr) {
            const int r = wave * 4 + rr;
            const float v = keybuf[r][lane];
            unsigned long long pend = __ballot(v < tau[rr]);
            while (pend) {
                const int s = __ffsll(pend) - 1;
                pend &= pend - 1;
                const float vs = __shfl(v, s);
                if (!(vs < tau[rr])) continue;
                const int js = j0 + s;
                const float pd = __shfl_up(dl[rr], 1);
                const int   pi = __shfl_up(il[rr], 1);
                const unsigned long long m = __ballot(dl[rr] <= vs);
                const int p = __popcll(m);
                if (lane == p)      { dl[rr] = vs; il[rr] = js; }
                else if (lane > p)  { dl[rr] = pd; il[rr] = pi; }
                tau[rr] = __shfl(dl[rr], NC - 1);
            }
        }
        __syncthreads();   // (2) keybuf consumed; drains vmcnt -> csb ready
    }

    // exact phase: golden-exact keys for the 64 candidates (bit-exact)
    #pragma unroll
    for (int rr = 0; rr < 4; ++rr) {
        const int r  = wave * 4 + rr;
        const int gi = R0 + r;
        const int ce = il[rr];
        const float* cp = embb + (size_t)ce * DD;
        float g = 0.f;
        #pragma unroll 8
        for (int k4 = 0; k4 < 32; ++k4) {
            const float4 qv = *(const float4*)&qsf[r][k4 * 4];
            const float4 cv = *(const float4*)(cp + k4 * 4);
            g = fmaf(qv.x, cv.x, g);
            g = fmaf(qv.y, cv.y, g);
            g = fmaf(qv.z, cv.z, g);
            g = fmaf(qv.w, cv.w, g);
        }
        const float tsum = __fadd_rn(sqq_s[r], sqb[ce]);
        float d2v = __fsub_rn(tsum, __fmul_rn(2.0f, g));
        d2v = fmaxf(d2v, 0.0f);
        const float ke = (float)sqrt((double)d2v);
        int rank = 0;
        for (int c = 0; c < NC; ++c) {
            const float kc = __shfl(ke, c);
            const int   jc = __shfl(ce, c);
            rank += (kc < ke) || (kc == ke && jc < ce);
        }
        if (rank < KK) {
            const size_t o = ((size_t)b * SS + gi) * KK + rank;
            out[o] = (float)ce;
            out[(size_t)BB * SS * KK + o] = ke;
        }
    }
}

// ---------- fallback path (R25, proven at 500 us) ----------
__global__ __launch_bounds__(256)
void sq_kernel(const float* __restrict__ emb, float* __restrict__ sqg) {
    const int t    = threadIdx.x;
    const int lane = t & 63;
    const int wid  = t >> 6;
    const int grp  = lane >> 4;
    const int gl   = lane & 15;
    const int row  = blockIdx.x * 16 + wid * 4 + grp;
    const float* rp = emb + (size_t)row * DD;
    const float p0 = rp[  0 + gl], p1 = rp[ 16 + gl], p2 = rp[ 32 + gl], p3 = rp[ 48 + gl];
    const float p4 = rp[ 64 + gl], p5 = rp[ 80 + gl], p6 = rp[ 96 + gl], p7 = rp[112 + gl];
    const float t0 = __fmul_rn(p0, p0), t1 = __fmul_rn(p1, p1);
    const float t2 = __fmul_rn(p2, p2), t3 = __fmul_rn(p3, p3);
    const float t4 = __fmul_rn(p4, p4), t5 = __fmul_rn(p5, p5);
    const float t6 = __fmul_rn(p6, p6), t7 = __fmul_rn(p7, p7);
    const float s = __fadd_rn(__fadd_rn(__fadd_rn(t0, t1), __fadd_rn(t2, t3)),
                              __fadd_rn(__fadd_rn(t4, t5), __fadd_rn(t6, t7)));
    const int gbase = lane & 48;
    const float u = __fadd_rn(s, __shfl(s, gbase + ((lane & 15) + 8)));
    const float w = __fadd_rn(u, __shfl(u, gbase + ((lane & 15) + 4)));
    const float w0 = __shfl(w, gbase + 0), w1 = __shfl(w, gbase + 1);
    const float w2 = __shfl(w, gbase + 2), w3 = __shfl(w, gbase + 3);
    if (gl == 0) sqg[row] = __fadd_rn(__fadd_rn(w0, w2), __fadd_rn(w1, w3));
}

__global__ __launch_bounds__(256, 4)
void knn_screen2_kernel(const float* __restrict__ emb, const float* __restrict__ sqg,
                        float* __restrict__ out) {
    __shared__ unsigned short qsb[QB][128];
    __shared__ unsigned short csb[CB][128];
    __shared__ float qsf[QB][128];
    __shared__ float keybuf[QB][CB];
    __shared__ float sqq_s[QB];
    __shared__ float sqc_s[CB];

    const int t    = threadIdx.x;
    const int lane = t & 63;
    const int wave = t >> 6;
    const int bx   = blockIdx.x;
    const int b    = bx >> 8;
    const int rb   = bx & 255;
    const int R0   = rb * QB;
    const float* embb = emb + (size_t)b * SS * DD;
    const float* sqb  = sqg + (size_t)b * SS;

    for (int i = t; i < QB * 32; i += 256) {
        const int r = i >> 5, c4 = i & 31;
        float4 v = *(const float4*)(embb + (size_t)(R0 + r) * DD + c4 * 4);
        *(float4*)&qsf[r][c4 * 4] = v;
        const int G = c4 >> 1;
        unsigned short* dst = &qsb[r][((G ^ (r & 7)) << 3) + (c4 & 1) * 4];
        dst[0] = f2bf(v.x); dst[1] = f2bf(v.y); dst[2] = f2bf(v.z); dst[3] = f2bf(v.w);
    }
    if (t < QB) sqq_s[t] = sqb[R0 + t];

    float dl[4] = {FINF, FINF, FINF, FINF};
    int   il[4] = {0, 0, 0, 0};
    float tau[4] = {FINF, FINF, FINF, FINF};
    const int arow = lane & 15;
    const int bcol = wave * 16 + (lane & 15);

    for (int tile = 0; tile < SS / CB; ++tile) {
        const int j0 = tile * CB;
        for (int i = t; i < CB * 32; i += 256) {
            const int r = i >> 5, c4 = i & 31;
            float4 v = *(const float4*)(embb + (size_t)(j0 + r) * DD + c4 * 4);
            const int G = c4 >> 1;
            unsigned short* dst = &csb[r][((G ^ (r & 7)) << 3) + (c4 & 1) * 4];
            dst[0] = f2bf(v.x); dst[1] = f2bf(v.y); dst[2] = f2bf(v.z); dst[3] = f2bf(v.w);
        }
        if (t < CB) sqc_s[t] = sqb[j0 + t];
        __syncthreads();

        f32x4 acc = {0.f, 0.f, 0.f, 0.f};
        #pragma unroll
        for (int ks = 0; ks < 4; ++ks) {
            const int kg = ks * 4 + (lane >> 4);
            short8v a  = *(const short8v*)&qsb[arow][(kg ^ (arow & 7)) << 3];
            short8v bf = *(const short8v*)&csb[bcol][(kg ^ (bcol & 7)) << 3];
            acc = __builtin_amdgcn_mfma_f32_16x16x32_bf16(a, bf, acc, 0, 0, 0);
        }
        {
            const int grow_base = (lane >> 4) * 4;
            #pragma unroll
            for (int q = 0; q < 4; ++q) {
                const int grow = grow_base + q;
                float d2v = sqq_s[grow] + sqc_s[bcol] - 2.0f * acc[q];
                if (R0 + grow == j0 + bcol) d2v = FINF;
                keybuf[grow][bcol] = d2v;
            }
        }
        __syncthreads();

        #pragma unroll
        for (int rr = 0; rr < 4; ++rr) {
            const int r = wave * 4 + rr;
            const float v = keybuf[r][lane];
            unsigned long long pend = __ballot(v < tau[rr]);
            while (pend) {
                const int s = __ffsll(pend) - 1;
                pend &= pend - 1;
                const float vs = __shfl(v, s);
                if (!(vs < tau[rr])) continue;
                const int js = j0 + s;
                const float pd = __shfl_up(dl[rr], 1);
                const int   pi = __shfl_up(il[rr], 1);
                const unsigned long long m = __ballot(dl[rr] <= vs);
                const int p = __popcll(m);
                if (lane == p)      { dl[rr] = vs; il[rr] = js; }
                else if (lane > p)  { dl[rr] = pd; il[rr] = pi; }
                tau[rr] = __shfl(dl[rr], NC - 1);
            }
        }
    }

    __syncthreads();
    #pragma unroll
    for (int rr = 0; rr < 4; ++rr) {
        const int r  = wave * 4 + rr;
        const int gi = R0 + r;
        const int ce = il[rr];
        const float* cp = embb + (size_t)ce * DD;
        float g = 0.f;
        #pragma unroll 8
        for (int k4 = 0; k4 < 32; ++k4) {
            const float4 qv = *(const float4*)&qsf[r][k4 * 4];
            const float4 cv = *(const float4*)(cp + k4 * 4);
            g = fmaf(qv.x, cv.x, g);
            g = fmaf(qv.y, cv.y, g);
            g = fmaf(qv.z, cv.z, g);
            g = fmaf(qv.w, cv.w, g);
        }
        const float tsum = __fadd_rn(sqq_s[r], sqb[ce]);
        float d2v = __fsub_rn(tsum, __fmul_rn(2.0f, g));
        d2v = fmaxf(d2v, 0.0f);
        const float ke = (float)sqrt((double)d2v);
        int rank = 0;
        for (int c = 0; c < NC; ++c) {
            const float kc = __shfl(ke, c);
            const int   jc = __shfl(ce, c);
            rank += (kc < ke) || (kc == ke && jc < ce);
        }
        if (rank < KK) {
            const size_t o = ((size_t)b * SS + gi) * KK + rank;
            out[o] = (float)ce;
            out[(size_t)BB * SS * KK + o] = ke;
        }
    }
}

extern "C" void kernel_launch(void* const* d_in, const int* in_sizes, int n_in,
                              void* d_out, int out_size, void* d_ws, size_t ws_size,
                              hipStream_t stream) {
    const float* emb = (const float*)d_in[0];
    float* out = (float*)d_out;
    float* sqg = (float*)d_ws;
    (void)in_sizes; (void)n_in; (void)out_size;
    const size_t need = 65536 + (size_t)BB * SS * 128 * 2;   // sq + bf16 emb = 4.26 MB
    if (ws_size >= need) {
        unsigned short* ebf = (unsigned short*)((char*)d_ws + 65536);
        prep_kernel<<<dim3(BB * SS / 16), dim3(256), 0, stream>>>(emb, sqg, ebf);
        knn_fast_kernel<<<dim3(BB * (SS / QB)), dim3(256), 0, stream>>>(emb, sqg, ebf, out);
    } else {
        sq_kernel<<<dim3(BB * SS / 16), dim3(256), 0, stream>>>(emb, sqg);
        knn_screen2_kernel<<<dim3(BB * (SS / QB)), dim3(256), 0, stream>>>(emb, sqg, out);
    }
}

// Round 27
// 390.306 us; speedup vs baseline: 2.5553x; 1.1290x over previous
//
#include <hip/hip_runtime.h>
#include <hip/hip_bf16.h>
#include <math.h>
#include <stdint.h>

#define BB 4
#define SS 4096
#define DD 128
#define KK 32
#define QB 16
#define CB 64
#define CB2 128
#define NC 64
#define FINF __builtin_inff()

typedef __attribute__((ext_vector_type(8))) short short8v;
typedef __attribute__((ext_vector_type(4))) float f32x4;

__device__ __forceinline__ unsigned short f2bf(float x) {
    __hip_bfloat16 h = __float2bfloat16(x);
    return *reinterpret_cast<unsigned short*>(&h);
}

__device__ __forceinline__ void gload16(const void* gsrc, void* ldsdst) {
    __builtin_amdgcn_global_load_lds(
        (const __attribute__((address_space(1))) unsigned int*)gsrc,
        (__attribute__((address_space(3))) unsigned int*)ldsdst, 16, 0, 0);
}

// ---------- prep: exact sq (proven) + bf16 pre-swizzled copy of emb ----------
__global__ __launch_bounds__(256)
void prep_kernel(const float* __restrict__ emb, float* __restrict__ sqg,
                 unsigned short* __restrict__ ebf) {
    const int t    = threadIdx.x;
    const int lane = t & 63;
    const int wid  = t >> 6;
    const int grp  = lane >> 4;
    const int gl   = lane & 15;
    const int row  = blockIdx.x * 16 + wid * 4 + grp;
    const float* rp = emb + (size_t)row * DD;

    const float p0 = rp[  0 + gl], p1 = rp[ 16 + gl], p2 = rp[ 32 + gl], p3 = rp[ 48 + gl];
    const float p4 = rp[ 64 + gl], p5 = rp[ 80 + gl], p6 = rp[ 96 + gl], p7 = rp[112 + gl];
    const float t0 = __fmul_rn(p0, p0), t1 = __fmul_rn(p1, p1);
    const float t2 = __fmul_rn(p2, p2), t3 = __fmul_rn(p3, p3);
    const float t4 = __fmul_rn(p4, p4), t5 = __fmul_rn(p5, p5);
    const float t6 = __fmul_rn(p6, p6), t7 = __fmul_rn(p7, p7);
    const float s = __fadd_rn(__fadd_rn(__fadd_rn(t0, t1), __fadd_rn(t2, t3)),
                              __fadd_rn(__fadd_rn(t4, t5), __fadd_rn(t6, t7)));
    const int gbase = lane & 48;
    const float u = __fadd_rn(s, __shfl(s, gbase + ((lane & 15) + 8)));
    const float w = __fadd_rn(u, __shfl(u, gbase + ((lane & 15) + 4)));
    const float w0 = __shfl(w, gbase + 0), w1 = __shfl(w, gbase + 1);
    const float w2 = __shfl(w, gbase + 2), w3 = __shfl(w, gbase + 3);
    if (gl == 0) sqg[row] = __fadd_rn(__fadd_rn(w0, w2), __fadd_rn(w1, w3));

    const float4 va = *(const float4*)(rp + gl * 8);
    const float4 vb = *(const float4*)(rp + gl * 8 + 4);
    short8v pk;
    pk[0] = (short)f2bf(va.x); pk[1] = (short)f2bf(va.y);
    pk[2] = (short)f2bf(va.z); pk[3] = (short)f2bf(va.w);
    pk[4] = (short)f2bf(vb.x); pk[5] = (short)f2bf(vb.y);
    pk[6] = (short)f2bf(vb.z); pk[7] = (short)f2bf(vb.w);
    const int gsw = gl ^ (row & 7);
    *(short8v*)&ebf[(size_t)row * 128 + gsw * 8] = pk;
}

// ---------- fast main: 8 waves, CB2=128 tile, chain-shortened insertion ----------
__global__ __launch_bounds__(512, 6)
void knn_fast2_kernel(const float* __restrict__ emb, const float* __restrict__ sqg,
                      const unsigned short* __restrict__ ebf, float* __restrict__ out) {
    __shared__ unsigned short qsb[QB][128];    // 4 KB  (swizzled bf16 q)
    __shared__ unsigned short csb[CB2][128];   // 32 KB (swizzled bf16 c tile)
    __shared__ float qsf[QB][128];             // 8 KB  (f32 q for exact phase)
    __shared__ float keybuf[QB][CB2];          // 8 KB
    __shared__ float sqq_s[QB];

    const int t    = threadIdx.x;
    const int lane = t & 63;
    const int wave = t >> 6;
    const int bx   = blockIdx.x;
    const int b    = bx >> 8;
    const int rb   = bx & 255;
    const int R0   = rb * QB;
    const float* embb = emb + (size_t)b * SS * DD;
    const float* sqb  = sqg + (size_t)b * SS;
    const unsigned short* ebfb = ebf + (size_t)b * SS * 128;

    // stage q: bf16 via gload_lds (first 4 waves), f32 via normal loads
    if (wave < 4)
        gload16((const char*)ebfb + (size_t)R0 * 256 + wave * 1024 + lane * 16,
                (char*)&qsb[0][0] + wave * 1024);
    {
        const int i = t;                        // QB*32 = 512 = blockDim
        const int r = i >> 5, c4 = i & 31;
        *(float4*)&qsf[r][c4 * 4] = *(const float4*)(embb + (size_t)(R0 + r) * DD + c4 * 4);
    }
    if (t < QB) sqq_s[t] = sqb[R0 + t];

    float dl[2]  = {FINF, FINF};
    int   il[2]  = {0, 0};
    float tau[2] = {FINF, FINF};

    const int arow = lane & 15;
    const int bcol = wave * 16 + (lane & 15);

    // preload tile 0 (32 KB: 8 waves x 4 gload16)
    #pragma unroll
    for (int c2 = 0; c2 < 4; ++c2)
        gload16((const char*)ebfb + (wave * 4 + c2) * 1024 + lane * 16,
                (char*)&csb[0][0] + (wave * 4 + c2) * 1024);
    __syncthreads();

    for (int tile = 0; tile < SS / CB2; ++tile) {
        const int j0 = tile * CB2;

        // phase B: MFMA gram + approx d2 keys
        f32x4 acc = {0.f, 0.f, 0.f, 0.f};
        #pragma unroll
        for (int ks = 0; ks < 4; ++ks) {
            const int kg = ks * 4 + (lane >> 4);
            short8v a  = *(const short8v*)&qsb[arow][(kg ^ (arow & 7)) << 3];
            short8v bf = *(const short8v*)&csb[bcol][(kg ^ (bcol & 7)) << 3];
            acc = __builtin_amdgcn_mfma_f32_16x16x32_bf16(a, bf, acc, 0, 0, 0);
        }
        {
            const float sqcv = sqb[j0 + bcol];
            const int grow_base = (lane >> 4) * 4;
            #pragma unroll
            for (int q = 0; q < 4; ++q) {
                const int grow = grow_base + q;
                float d2v = sqq_s[grow] + sqcv - 2.0f * acc[q];
                if (R0 + grow == j0 + bcol) d2v = FINF;
                keybuf[grow][bcol] = d2v;
            }
        }
        __syncthreads();   // (1) csb consumed, keybuf ready

        // prefetch next tile into csb (overlaps with phase C)
        if (tile + 1 < SS / CB2) {
            const size_t base = (size_t)(j0 + CB2) * 256;
            #pragma unroll
            for (int c2 = 0; c2 < 4; ++c2)
                gload16((const char*)ebfb + base + (wave * 4 + c2) * 1024 + lane * 16,
                        (char*)&csb[0][0] + (wave * 4 + c2) * 1024);
        }

        // phase C: chain-shortened top-64 insertion; wave owns rows wave*2, wave*2+1
        #pragma unroll
        for (int rr = 0; rr < 2; ++rr) {
            const int r = wave * 2 + rr;
            const float v0 = keybuf[r][lane];
            const float v1 = keybuf[r][64 + lane];
            // stale tau is safe: stale survivors insert at p>=64 -> no-op
            unsigned long long pend0 = __ballot(v0 < tau[rr]);
            unsigned long long pend1 = __ballot(v1 < tau[rr]);
            while (pend0) {
                const int s = __ffsll(pend0) - 1;
                pend0 &= pend0 - 1;
                const float vs = __shfl(v0, s);
                const int js = j0 + s;
                const float pd = __shfl_up(dl[rr], 1);
                const int   pi = __shfl_up(il[rr], 1);
                const unsigned long long m = __ballot(dl[rr] <= vs);
                const int p = __popcll(m);
                if (lane == p)      { dl[rr] = vs; il[rr] = js; }
                else if (lane > p)  { dl[rr] = pd; il[rr] = pi; }
            }
            while (pend1) {
                const int s = __ffsll(pend1) - 1;
                pend1 &= pend1 - 1;
                const float vs = __shfl(v1, s);
                const int js = j0 + 64 + s;
                const float pd = __shfl_up(dl[rr], 1);
                const int   pi = __shfl_up(il[rr], 1);
                const unsigned long long m = __ballot(dl[rr] <= vs);
                const int p = __popcll(m);
                if (lane == p)      { dl[rr] = vs; il[rr] = js; }
                else if (lane > p)  { dl[rr] = pd; il[rr] = pi; }
            }
            tau[rr] = __shfl(dl[rr], NC - 1);   // once per tile per row
        }
        __syncthreads();   // (2) keybuf consumed; drains vmcnt -> csb ready
    }

    // exact phase: golden-exact keys for the 64 candidates (bit-exact)
    #pragma unroll
    for (int rr = 0; rr < 2; ++rr) {
        const int r  = wave * 2 + rr;
        const int gi = R0 + r;
        const int ce = il[rr];
        const float* cp = embb + (size_t)ce * DD;
        float g = 0.f;
        #pragma unroll 8
        for (int k4 = 0; k4 < 32; ++k4) {
            const float4 qv = *(const float4*)&qsf[r][k4 * 4];
            const float4 cv = *(const float4*)(cp + k4 * 4);
            g = fmaf(qv.x, cv.x, g);
            g = fmaf(qv.y, cv.y, g);
            g = fmaf(qv.z, cv.z, g);
            g = fmaf(qv.w, cv.w, g);
        }
        const float tsum = __fadd_rn(sqq_s[r], sqb[ce]);
        float d2v = __fsub_rn(tsum, __fmul_rn(2.0f, g));
        d2v = fmaxf(d2v, 0.0f);
        const float ke = (float)sqrt((double)d2v);
        int rank = 0;
        for (int c = 0; c < NC; ++c) {
            const float kc = __shfl(ke, c);
            const int   jc = __shfl(ce, c);
            rank += (kc < ke) || (kc == ke && jc < ce);
        }
        if (rank < KK) {
            const size_t o = ((size_t)b * SS + gi) * KK + rank;
            out[o] = (float)ce;
            out[(size_t)BB * SS * KK + o] = ke;
        }
    }
}

// ---------- fallback path (R25, proven) ----------
__global__ __launch_bounds__(256)
void sq_kernel(const float* __restrict__ emb, float* __restrict__ sqg) {
    const int t    = threadIdx.x;
    const int lane = t & 63;
    const int wid  = t >> 6;
    const int grp  = lane >> 4;
    const int gl   = lane & 15;
    const int row  = blockIdx.x * 16 + wid * 4 + grp;
    const float* rp = emb + (size_t)row * DD;
    const float p0 = rp[  0 + gl], p1 = rp[ 16 + gl], p2 = rp[ 32 + gl], p3 = rp[ 48 + gl];
    const float p4 = rp[ 64 + gl], p5 = rp[ 80 + gl], p6 = rp[ 96 + gl], p7 = rp[112 + gl];
    const float t0 = __fmul_rn(p0, p0), t1 = __fmul_rn(p1, p1);
    const float t2 = __fmul_rn(p2, p2), t3 = __fmul_rn(p3, p3);
    const float t4 = __fmul_rn(p4, p4), t5 = __fmul_rn(p5, p5);
    const float t6 = __fmul_rn(p6, p6), t7 = __fmul_rn(p7, p7);
    const float s = __fadd_rn(__fadd_rn(__fadd_rn(t0, t1), __fadd_rn(t2, t3)),
                              __fadd_rn(__fadd_rn(t4, t5), __fadd_rn(t6, t7)));
    const int gbase = lane & 48;
    const float u = __fadd_rn(s, __shfl(s, gbase + ((lane & 15) + 8)));
    const float w = __fadd_rn(u, __shfl(u, gbase + ((lane & 15) + 4)));
    const float w0 = __shfl(w, gbase + 0), w1 = __shfl(w, gbase + 1);
    const float w2 = __shfl(w, gbase + 2), w3 = __shfl(w, gbase + 3);
    if (gl == 0) sqg[row] = __fadd_rn(__fadd_rn(w0, w2), __fadd_rn(w1, w3));
}

__global__ __launch_bounds__(256, 4)
void knn_screen2_kernel(const float* __restrict__ emb, const float* __restrict__ sqg,
                        float* __restrict__ out) {
    __shared__ unsigned short qsb[QB][128];
    __shared__ unsigned short csb[CB][128];
    __shared__ float qsf[QB][128];
    __shared__ float keybuf[QB][CB];
    __shared__ float sqq_s[QB];
    __shared__ float sqc_s[CB];

    const int t    = threadIdx.x;
    const int lane = t & 63;
    const int wave = t >> 6;
    const int bx   = blockIdx.x;
    const int b    = bx >> 8;
    const int rb   = bx & 255;
    const int R0   = rb * QB;
    const float* embb = emb + (size_t)b * SS * DD;
    const float* sqb  = sqg + (size_t)b * SS;

    for (int i = t; i < QB * 32; i += 256) {
        const int r = i >> 5, c4 = i & 31;
        float4 v = *(const float4*)(embb + (size_t)(R0 + r) * DD + c4 * 4);
        *(float4*)&qsf[r][c4 * 4] = v;
        const int G = c4 >> 1;
        unsigned short* dst = &qsb[r][((G ^ (r & 7)) << 3) + (c4 & 1) * 4];
        dst[0] = f2bf(v.x); dst[1] = f2bf(v.y); dst[2] = f2bf(v.z); dst[3] = f2bf(v.w);
    }
    if (t < QB) sqq_s[t] = sqb[R0 + t];

    float dl[4] = {FINF, FINF, FINF, FINF};
    int   il[4] = {0, 0, 0, 0};
    float tau[4] = {FINF, FINF, FINF, FINF};
    const int arow = lane & 15;
    const int bcol = wave * 16 + (lane & 15);

    for (int tile = 0; tile < SS / CB; ++tile) {
        const int j0 = tile * CB;
        for (int i = t; i < CB * 32; i += 256) {
            const int r = i >> 5, c4 = i & 31;
            float4 v = *(const float4*)(embb + (size_t)(j0 + r) * DD + c4 * 4);
            const int G = c4 >> 1;
            unsigned short* dst = &csb[r][((G ^ (r & 7)) << 3) + (c4 & 1) * 4];
            dst[0] = f2bf(v.x); dst[1] = f2bf(v.y); dst[2] = f2bf(v.z); dst[3] = f2bf(v.w);
        }
        if (t < CB) sqc_s[t] = sqb[j0 + t];
        __syncthreads();

        f32x4 acc = {0.f, 0.f, 0.f, 0.f};
        #pragma unroll
        for (int ks = 0; ks < 4; ++ks) {
            const int kg = ks * 4 + (lane >> 4);
            short8v a  = *(const short8v*)&qsb[arow][(kg ^ (arow & 7)) << 3];
            short8v bf = *(const short8v*)&csb[bcol][(kg ^ (bcol & 7)) << 3];
            acc = __builtin_amdgcn_mfma_f32_16x16x32_bf16(a, bf, acc, 0, 0, 0);
        }
        {
            const int grow_base = (lane >> 4) * 4;
            #pragma unroll
            for (int q = 0; q < 4; ++q) {
                const int grow = grow_base + q;
                float d2v = sqq_s[grow] + sqc_s[bcol] - 2.0f * acc[q];
                if (R0 + grow == j0 + bcol) d2v = FINF;
                keybuf[grow][bcol] = d2v;
            }
        }
        __syncthreads();

        #pragma unroll
        for (int rr = 0; rr < 4; ++rr) {
            const int r = wave * 4 + rr;
            const float v = keybuf[r][lane];
            unsigned long long pend = __ballot(v < tau[rr]);
            while (pend) {
                const int s = __ffsll(pend) - 1;
                pend &= pend - 1;
                const float vs = __shfl(v, s);
                if (!(vs < tau[rr])) continue;
                const int js = j0 + s;
                const float pd = __shfl_up(dl[rr], 1);
                const int   pi = __shfl_up(il[rr], 1);
                const unsigned long long m = __ballot(dl[rr] <= vs);
                const int p = __popcll(m);
                if (lane == p)      { dl[rr] = vs; il[rr] = js; }
                else if (lane > p)  { dl[rr] = pd; il[rr] = pi; }
                tau[rr] = __shfl(dl[rr], NC - 1);
            }
        }
    }

    __syncthreads();
    #pragma unroll
    for (int rr = 0; rr < 4; ++rr) {
        const int r  = wave * 4 + rr;
        const int gi = R0 + r;
        const int ce = il[rr];
        const float* cp = embb + (size_t)ce * DD;
        float g = 0.f;
        #pragma unroll 8
        for (int k4 = 0; k4 < 32; ++k4) {
            const float4 qv = *(const float4*)&qsf[r][k4 * 4];
            const float4 cv = *(const float4*)(cp + k4 * 4);
            g = fmaf(qv.x, cv.x, g);
            g = fmaf(qv.y, cv.y, g);
            g = fmaf(qv.z, cv.z, g);
            g = fmaf(qv.w, cv.w, g);
        }
        const float tsum = __fadd_rn(sqq_s[r], sqb[ce]);
        float d2v = __fsub_rn(tsum, __fmul_rn(2.0f, g));
        d2v = fmaxf(d2v, 0.0f);
        const float ke = (float)sqrt((double)d2v);
        int rank = 0;
        for (int c = 0; c < NC; ++c) {
            const float kc = __shfl(ke, c);
            const int   jc = __shfl(ce, c);
            rank += (kc < ke) || (kc == ke && jc < ce);
        }
        if (rank < KK) {
            const size_t o = ((size_t)b * SS + gi) * KK + rank;
            out[o] = (float)ce;
            out[(size_t)BB * SS * KK + o] = ke;
        }
    }
}

extern "C" void kernel_launch(void* const* d_in, const int* in_sizes, int n_in,
                              void* d_out, int out_size, void* d_ws, size_t ws_size,
                              hipStream_t stream) {
    const float* emb = (const float*)d_in[0];
    float* out = (float*)d_out;
    float* sqg = (float*)d_ws;
    (void)in_sizes; (void)n_in; (void)out_size;
    const size_t need = 65536 + (size_t)BB * SS * 128 * 2;
    if (ws_size >= need) {
        unsigned short* ebf = (unsigned short*)((char*)d_ws + 65536);
        prep_kernel<<<dim3(BB * SS / 16), dim3(256), 0, stream>>>(emb, sqg, ebf);
        knn_fast2_kernel<<<dim3(BB * (SS / QB)), dim3(512), 0, stream>>>(emb, sqg, ebf, out);
    } else {
        sq_kernel<<<dim3(BB * SS / 16), dim3(256), 0, stream>>>(emb, sqg);
        knn_screen2_kernel<<<dim3(BB * (SS / QB)), dim3(256), 0, stream>>>(emb, sqg, out);
    }
}